// Round 1
// 698.720 us; speedup vs baseline: 1.1165x; 1.1165x over previous
//
#include <hip/hip_runtime.h>

#define N_IC 10
#define N_OC 32
#define PPB 128          // points per block in k1
#define BLK 256
#define PAD 11           // LDS stride pad: 11 coprime 32 -> conflict-free
#define NPIL 50000

typedef float f4 __attribute__((ext_vector_type(4)));

// k1: fused linear + BN(inference) + relu, write out[:,0:32], filtered atomicMax into pillar buffer
__global__ __launch_bounds__(BLK) void pfn_k1(
    const float* __restrict__ in, const int* __restrict__ unq,
    const float* __restrict__ W, const float* __restrict__ gamma,
    const float* __restrict__ beta, const float* __restrict__ rmean,
    const float* __restrict__ rvar,
    float* __restrict__ out, unsigned* __restrict__ pmax, int n)
{
    __shared__ float sW[N_OC][PAD];
    __shared__ float sB[N_OC];
    __shared__ float sIn[PPB][PAD];
    __shared__ int   sPil[PPB];

    const int t = threadIdx.x;
    // fold BN into weights (32 threads, once per block; precise inv-std)
    if (t < N_OC) {
        float s = gamma[t] / sqrtf(rvar[t] + 1e-3f);
        sB[t] = fmaf(-rmean[t], s, beta[t]);
        #pragma unroll
        for (int k = 0; k < N_IC; ++k) sW[t][k] = W[t * N_IC + k] * s;
    }
    const long long base = (long long)blockIdx.x * PPB;
    // stage 128 points x 10 ch, coalesced global read -> padded LDS (NT: streamed once)
    for (int i = t; i < PPB * N_IC; i += BLK) {
        int p = i / N_IC;
        int k = i - p * N_IC;
        long long gp = base + p;
        sIn[p][k] = (gp < (long long)n) ? __builtin_nontemporal_load(&in[gp * N_IC + k]) : 0.f;
    }
    if (t < PPB) {
        long long gp = base + t;
        sPil[t] = (gp < (long long)n) ? unq[gp] : 0;   // unq stays cacheable (k2 re-reads)
    }
    __syncthreads();

    const int o   = t & 31;   // output channel
    const int sub = t >> 5;   // which point of the group of 8
    float w[N_IC];
    #pragma unroll
    for (int k = 0; k < N_IC; ++k) w[k] = sW[o][k];
    const float b = sB[o];

    #pragma unroll
    for (int it = 0; it < PPB; it += (BLK / 32)) {
        const int lp = it + sub;
        const long long gp = base + lp;
        if (gp < (long long)n) {
            float acc = b;
            #pragma unroll
            for (int k = 0; k < N_IC; ++k) acc = fmaf(sIn[lp][k], w[k], acc);
            float v = fmaxf(acc, 0.f);
            // channels 0..31 of row gp: bytes 0..127 -> two full 64B lines, coalesced.
            // NT store: out is write-once, never re-read by us -> keep L2 for pmax.
            __builtin_nontemporal_store(v, &out[gp * 64 + o]);
            // Filtered scatter-max: read current max (coalesced 128B L2 segment,
            // fully pipelined) and only issue the RMW on improvement. Stale reads
            // are safe (monotone buffer, stale <= truth -> never wrongly skip).
            // Drops atomics ~32M -> ~7M and kills the 32-consecutive-word
            // per-point RMW bank serialization.
            if (v > 0.f) {
                unsigned* addr = &pmax[(unsigned)sPil[lp] * N_OC + o];
                if (v > __uint_as_float(*addr))
                    atomicMax(addr, __float_as_uint(v));
            }
        }
    }
}

// k2: gather per-pillar max back, write out[:,32:64] as float4 (8 lanes/point)
__global__ __launch_bounds__(BLK) void pfn_k2(
    const int* __restrict__ unq, const f4* __restrict__ pmax4,
    f4* __restrict__ out4, int n)
{
    long long tid = (long long)blockIdx.x * BLK + threadIdx.x;
    long long p = tid >> 3;          // point index
    int q = (int)(tid & 7);          // which float4 of the 8 in the xmax half-row
    if (p < (long long)n) {
        int pil = unq[p];                           // broadcast across 8 lanes
        f4 v = pmax4[(long long)pil * 8 + q];       // 128B row gather, L2-resident
        __builtin_nontemporal_store(v, &out4[p * 16 + 8 + q]);  // full 64B lines
    }
}

extern "C" void kernel_launch(void* const* d_in, const int* in_sizes, int n_in,
                              void* d_out, int out_size, void* d_ws, size_t ws_size,
                              hipStream_t stream) {
    const float* in    = (const float*)d_in[0];
    const int*   unq   = (const int*)d_in[1];
    const float* W     = (const float*)d_in[2];
    const float* gamma = (const float*)d_in[3];
    const float* beta  = (const float*)d_in[4];
    const float* rmean = (const float*)d_in[5];
    const float* rvar  = (const float*)d_in[6];
    const int n = in_sizes[1];                 // 2,000,000 points
    float* out = (float*)d_out;
    unsigned* pmax = (unsigned*)d_ws;

    size_t need = (size_t)NPIL * N_OC * sizeof(unsigned);   // 6.4 MB
    hipMemsetAsync(d_ws, 0, need, stream);

    int g1 = (n + PPB - 1) / PPB;
    pfn_k1<<<g1, BLK, 0, stream>>>(in, unq, W, gamma, beta, rmean, rvar, out, pmax, n);

    long long threads2 = (long long)n * 8;                  // 8 lanes per point
    int g2 = (int)((threads2 + BLK - 1) / BLK);
    pfn_k2<<<g2, BLK, 0, stream>>>(unq, (const f4*)d_ws, (f4*)out, n);
}